// Round 5
// baseline (678.617 us; speedup 1.0000x reference)
//
#include <hip/hip_runtime.h>
#include <hip/hip_bf16.h>

// Bahdanau attention, MI355X. B=32, S=2048, H=1024, HL=2048.
// d_out: context[32,1,1024] ++ weights[32,1,2048]  (fp32)
//
// R10: kb16 pre-pass DELETED. Score GEMM stages A as raw fp32 keys via
// global_load_lds with the XOR permutation applied to the per-lane GLOBAL
// source address (linear LDS dest, swizzled read — rule #21 compliant);
// fp32->bf16 conversion happens at frag-read time (16 cvt_pk/thread/K-step,
// hidden under 32 MFMA). A-swizzle: 128B rows, 8x16B chunks,
// slot = chunk ^ (row&7) -> 2 lanes/bank-group per quarter-wave.
// qproj+uat fused into prep_k (role-split). ctx_k atomic (R9).
//
// ws layout: qws 128K | uat 2M | score 256K

typedef __attribute__((ext_vector_type(8))) short short8;
typedef __attribute__((ext_vector_type(4))) float floatx4;

typedef const __attribute__((address_space(1))) unsigned int gu32;
typedef __attribute__((address_space(3))) unsigned int lu32;

__device__ __forceinline__ unsigned short f2bf(float f) {
    union { float f; unsigned int u; } c; c.f = f;
    unsigned int u = c.u + 0x7fffu + ((c.u >> 16) & 1u);  // RNE
    return (unsigned short)(u >> 16);
}

// two fp32 -> packed bf16 pair (lo in bits 0..15), RNE either way
__device__ __forceinline__ unsigned int f2bf2(float lo, float hi) {
#if __has_builtin(__builtin_amdgcn_cvt_pk_bf16_f32)
    auto r = __builtin_amdgcn_cvt_pk_bf16_f32(lo, hi);
    unsigned int u; __builtin_memcpy(&u, &r, 4);
    return u;
#else
    return (unsigned int)f2bf(lo) | ((unsigned int)f2bf(hi) << 16);
#endif
}

// async global->LDS, 16B per lane; lane i's data lands at ldsbase + i*16.
__device__ __forceinline__ void gld16(const void* g, const void* l) {
    __builtin_amdgcn_global_load_lds(
        (gu32*)(uintptr_t)g,
        (lu32*)(unsigned int)(uintptr_t)l,
        16, 0, 0);
}

// ---- K1: fused prep: qproj (blocks 0..511) + uat (blocks 512..767) ----
// qproj: q[b,h] = sum_d query[b,d]*Wa[d,h] + Wa_b[h] + Ua_b[h] (fp32 exact)
// uat:   uat[h][d] = bf16(Ua[d][h])
__global__ __launch_bounds__(256) void prep_k(
    const float* __restrict__ query, const float* __restrict__ Wa,
    const float* __restrict__ Wab, const float* __restrict__ Uab,
    const float* __restrict__ Ua,
    float* __restrict__ qws, unsigned short* __restrict__ uat)
{
    const int tid = threadIdx.x;
    if (blockIdx.x < 512) {
        __shared__ float qs[2048];
        __shared__ float red[16*64];
        const int b = blockIdx.x >> 4, hc = blockIdx.x & 15;
        #pragma unroll
        for (int i = 0; i < 8; i++) qs[tid + 256*i] = query[b*2048 + tid + 256*i];
        __syncthreads();
        const int hq = tid & 15;      // h-quad within 64-h tile
        const int dg = tid >> 4;      // d-group (128 d each)
        const float4* wp = reinterpret_cast<const float4*>(Wa + (size_t)(dg*128)*1024 + hc*64 + hq*4);
        const float* qp = qs + dg*128;
        float4 a0; a0.x = a0.y = a0.z = a0.w = 0.f;
        float4 a1; a1.x = a1.y = a1.z = a1.w = 0.f;
        #pragma unroll 4
        for (int d = 0; d < 128; d += 2) {
            float q0 = qp[d], q1 = qp[d+1];
            float4 w0 = wp[(size_t)d*256];
            float4 w1 = wp[(size_t)(d+1)*256];
            a0.x += q0*w0.x; a0.y += q0*w0.y; a0.z += q0*w0.z; a0.w += q0*w0.w;
            a1.x += q1*w1.x; a1.y += q1*w1.y; a1.z += q1*w1.z; a1.w += q1*w1.w;
        }
        a0.x += a1.x; a0.y += a1.y; a0.z += a1.z; a0.w += a1.w;
        *reinterpret_cast<float4*>(red + dg*64 + hq*4) = a0;
        __syncthreads();
        if (tid < 64) {
            float v = 0.f;
            #pragma unroll
            for (int g = 0; g < 16; g++) v += red[g*64 + tid];
            int hh = hc*64 + tid;
            qws[b*1024 + hh] = v + Wab[hh] + Uab[hh];
        }
    } else {
        __shared__ unsigned short t[64][65];
        const int q = blockIdx.x - 512;
        const int x = tid & 63, yy = tid >> 6;
        const int d0 = (q >> 4)*64, h0 = (q & 15)*64;
        #pragma unroll
        for (int i = 0; i < 16; i++) {
            int y = yy*16 + i;
            t[y][x] = f2bf(Ua[(size_t)(d0+y)*1024 + h0 + x]);
        }
        __syncthreads();
        #pragma unroll
        for (int i = 0; i < 16; i++) {
            int y = yy*16 + i;
            uat[(size_t)(h0+y)*1024 + d0 + x] = t[x][y];
        }
    }
}

// ---- K3: score GEMM 128(s) x 256(h), both operands via global_load_lds ----
// A (fp32 keys, direct): LDS rows 128B = 8 chunks of 16B; chunk c of row r
//   stored at slot c^(r&7). gld16 dest is LINEAR; the permutation is applied
//   to the per-lane GLOBAL src: instr i, thread t -> row = i*32 + (t>>3),
//   src chunk = (t&7) ^ ((t>>3)&7).
//   Frag read: 2x ds_read_b128 at row*128 + ((2q+j)^(r&7))*16, then 4 cvt_pk.
// B (bf16 uat): rows 64B, slot = chunk^((row>>1)&3), per-lane src offset
//   (proven 0-conflict R4 scheme).
// Double-buffered, ONE barrier per K-step; 32 MFMA/thread/K-step.
// Epilogue: tanh + Va dot + atomicAdd into score[32][2048].
__global__ __launch_bounds__(256) void score_gemm_fast(
    const float* __restrict__ keys,           // [32][2048][1024] fp32
    const unsigned short* __restrict__ uat,   // [1024][1024] bf16 [h][d]
    const float* __restrict__ qws,            // [32][1024]
    const float* __restrict__ Va,             // [1024]
    float* __restrict__ score)                // [32][2048] (pre-zeroed)
{
    __shared__ float          aSf[2][128*32]; // 2 x 16KB (fp32 A tiles)
    __shared__ unsigned short bS[2][256*32];  // 2 x 16KB (bf16 B tiles)
    const int tid = threadIdx.x;
    const int b  = blockIdx.z;
    const int s0 = blockIdx.x * 128;
    const int h0 = blockIdx.y * 256;
    const int lane = tid & 63, wave = tid >> 6;
    const int quad = lane >> 4, l15 = lane & 15;
    const int wm = (wave & 1) * 64, wn = (wave >> 1) * 128;

    // B-staging source (runtime-permuted, proven)
    const int srow = lane >> 2;
    const int schunk = (lane & 3) ^ ((srow >> 1) & 3);
    const unsigned short* ubase = uat + (size_t)h0*1024;
    size_t boff[4];
    #pragma unroll
    for (int u = 0; u < 4; u++) {
        int cg = wave*4 + u;                  // chunk-group 0..15 (16 rows each)
        boff[u] = (size_t)(cg*16 + srow)*1024 + schunk*8;
    }

    // A-staging source (fp32, inverse-permuted per-lane):
    // instr i: row = i*32 + (tid>>3); src 16B-chunk = (tid&7)^((tid>>3)&7)
    const float* kA = keys + (size_t)(b*2048 + s0)*1024;
    const int arow = tid >> 3;
    const int acx  = (tid & 7) ^ ((tid >> 3) & 7);
    size_t aoff[4];
    #pragma unroll
    for (int i = 0; i < 4; i++)
        aoff[i] = (size_t)(i*32 + arow)*1024 + acx*4;

    floatx4 acc[4][8];
    #pragma unroll
    for (int i = 0; i < 4; i++)
        #pragma unroll
        for (int j = 0; j < 8; j++) acc[i][j] = (floatx4)0.0f;

    // ---- prologue: stage tile 0 into buffer 0 ----
    #pragma unroll
    for (int i = 0; i < 4; i++)
        gld16(kA + aoff[i], (unsigned short*)aSf[0] + i*2048 + wave*512);
    #pragma unroll
    for (int u = 0; u < 4; u++)
        gld16(ubase + boff[u], bS[0] + (wave*4 + u)*512);
    __syncthreads();

    int cur = 0;
    for (int kt = 0; kt < 31; ++kt) {
        const int nxt = cur ^ 1;
        const int k1 = (kt + 1) << 5;   // k offset in elements (fp32 A, bf16 B)

        // prefetch tile kt+1 into idle buffer (8 async instrs, no VGPR traffic)
        #pragma unroll
        for (int i = 0; i < 4; i++)
            gld16(kA + aoff[i] + k1, (unsigned short*)aSf[nxt] + i*2048 + wave*512);
        #pragma unroll
        for (int u = 0; u < 4; u++)
            gld16(ubase + boff[u] + k1, bS[nxt] + (wave*4 + u)*512);

        // compute tile kt from buf cur
        short8 af[4], bf8[8];
        #pragma unroll
        for (int i = 0; i < 4; i++) {
            int row = wm + 16*i + l15;
            const float* rp = aSf[cur] + row*32;
            float4 v0 = *reinterpret_cast<const float4*>(rp + (((2*quad)   ^ (row&7)) * 4));
            float4 v1 = *reinterpret_cast<const float4*>(rp + (((2*quad+1) ^ (row&7)) * 4));
            union { uint4 u; short8 s; } cv;
            cv.u.x = f2bf2(v0.x, v0.y); cv.u.y = f2bf2(v0.z, v0.w);
            cv.u.z = f2bf2(v1.x, v1.y); cv.u.w = f2bf2(v1.z, v1.w);
            af[i] = cv.s;
        }
        #pragma unroll
        for (int j = 0; j < 8; j++) {
            int row = wn + 16*j + l15;
            bf8[j] = *reinterpret_cast<const short8*>(bS[cur] + row*32 + ((quad ^ ((row>>1)&3)) * 8));
        }
        #pragma unroll
        for (int i = 0; i < 4; i++)
            #pragma unroll
            for (int j = 0; j < 8; j++)
                acc[i][j] = __builtin_amdgcn_mfma_f32_16x16x32_bf16(af[i], bf8[j], acc[i][j], 0, 0, 0);

        __syncthreads();   // drains prefetch vmcnt + frag lgkm; one barrier/K-step
        cur = nxt;
    }

    // ---- last tile: compute only ----
    {
        short8 af[4], bf8[8];
        #pragma unroll
        for (int i = 0; i < 4; i++) {
            int row = wm + 16*i + l15;
            const float* rp = aSf[cur] + row*32;
            float4 v0 = *reinterpret_cast<const float4*>(rp + (((2*quad)   ^ (row&7)) * 4));
            float4 v1 = *reinterpret_cast<const float4*>(rp + (((2*quad+1) ^ (row&7)) * 4));
            union { uint4 u; short8 s; } cv;
            cv.u.x = f2bf2(v0.x, v0.y); cv.u.y = f2bf2(v0.z, v0.w);
            cv.u.z = f2bf2(v1.x, v1.y); cv.u.w = f2bf2(v1.z, v1.w);
            af[i] = cv.s;
        }
        #pragma unroll
        for (int j = 0; j < 8; j++) {
            int row = wn + 16*j + l15;
            bf8[j] = *reinterpret_cast<const short8*>(bS[cur] + row*32 + ((quad ^ ((row>>1)&3)) * 8));
        }
        #pragma unroll
        for (int i = 0; i < 4; i++)
            #pragma unroll
            for (int j = 0; j < 8; j++)
                acc[i][j] = __builtin_amdgcn_mfma_f32_16x16x32_bf16(af[i], bf8[j], acc[i][j], 0, 0, 0);
    }

    // epilogue: p[s] = sum_n Va[n]*tanh(q[n]+k[s,n]); C-layout: n=lane&15, m=quad*4+reg
    float qv[8], vav[8];
    #pragma unroll
    for (int j = 0; j < 8; j++) {
        int n = h0 + wn + 16*j + l15;
        qv[j]  = qws[b*1024 + n];
        vav[j] = Va[n];
    }
    #pragma unroll
    for (int i = 0; i < 4; i++) {
        #pragma unroll
        for (int r = 0; r < 4; r++) {
            float p = 0.f;
            #pragma unroll
            for (int j = 0; j < 8; j++) {
                float x = qv[j] + acc[i][j][r];
                float e = __expf(2.f * x);                       // tanh = 1 - 2/(e^{2x}+1)
                float t = 1.f - 2.f * __builtin_amdgcn_rcpf(e + 1.f);
                p += vav[j] * t;
            }
            #pragma unroll
            for (int off = 1; off < 16; off <<= 1) p += __shfl_xor(p, off, 64);
            if (l15 == 0) {
                int m = wm + 16*i + quad*4 + r;
                atomicAdd(score + (size_t)b*2048 + s0 + m, p);
            }
        }
    }
}

// ---- K4: softmax over s per batch (single-pass; score pre-reduced) ----
__global__ __launch_bounds__(256) void softmax_k(const float* __restrict__ score,
                                                 float* __restrict__ out_w)
{
    const int tid = threadIdx.x;
    const int b = blockIdx.x;
    __shared__ float wred[4], wred2[4];
    float sc[8];
    float mx = -3.0e38f;
    #pragma unroll
    for (int i = 0; i < 8; i++) {
        sc[i] = score[(size_t)b*2048 + tid + 256*i];
        mx = fmaxf(mx, sc[i]);
    }
    #pragma unroll
    for (int off = 32; off >= 1; off >>= 1) mx = fmaxf(mx, __shfl_xor(mx, off, 64));
    if ((tid & 63) == 0) wred[tid >> 6] = mx;
    __syncthreads();
    mx = fmaxf(fmaxf(wred[0], wred[1]), fmaxf(wred[2], wred[3]));
    float e[8]; float lsum = 0.f;
    #pragma unroll
    for (int i = 0; i < 8; i++) { e[i] = __expf(sc[i] - mx); lsum += e[i]; }
    #pragma unroll
    for (int off = 32; off >= 1; off >>= 1) lsum += __shfl_xor(lsum, off, 64);
    if ((tid & 63) == 0) wred2[tid >> 6] = lsum;
    __syncthreads();
    float inv = 1.0f / (wred2[0] + wred2[1] + wred2[2] + wred2[3]);
    #pragma unroll
    for (int i = 0; i < 8; i++) out_w[b*2048 + tid + 256*i] = e[i] * inv;
}

// ---- K5: context accumulated directly into out_ctx via atomics ----
__global__ __launch_bounds__(256) void ctx_k(const float* __restrict__ keys,
                                             const float* __restrict__ w,
                                             float* __restrict__ out_ctx, int sper)
{
    const int tid = threadIdx.x;
    const int b = blockIdx.x, sc = blockIdx.y;
    const float4* k4 = reinterpret_cast<const float4*>(keys) + (size_t)(b*2048 + sc*sper)*256;
    const float* wp = w + b*2048 + sc*sper;
    float4 a; a.x = a.y = a.z = a.w = 0.f;
    #pragma unroll 4
    for (int s = 0; s < sper; s++) {
        float wv = wp[s];
        float4 kv = k4[(size_t)s*256 + tid];
        a.x += wv*kv.x; a.y += wv*kv.y; a.z += wv*kv.z; a.w += wv*kv.w;
    }
    float* o = out_ctx + (size_t)b*1024 + tid*4;
    atomicAdd(o + 0, a.x);
    atomicAdd(o + 1, a.y);
    atomicAdd(o + 2, a.z);
    atomicAdd(o + 3, a.w);
}

extern "C" void kernel_launch(void* const* d_in, const int* in_sizes, int n_in,
                              void* d_out, int out_size, void* d_ws, size_t ws_size,
                              hipStream_t stream)
{
    const float* query = (const float*)d_in[0];
    const float* keys  = (const float*)d_in[1];
    const float* Wa_w  = (const float*)d_in[2];
    const float* Wa_b  = (const float*)d_in[3];
    const float* Ua_w  = (const float*)d_in[4];
    const float* Ua_b  = (const float*)d_in[5];
    const float* Va_w  = (const float*)d_in[6];
    // d_in[7] (Va_b) is a uniform shift on scores -> softmax-invariant; unused.

    char* ws = (char*)d_ws;
    float*          qws   = (float*)(ws);                       // 128 KiB
    unsigned short* uat   = (unsigned short*)(ws + 131072);     // 2 MiB
    float*          score = (float*)(ws + 131072 + 2097152);    // 256 KiB

    float* out_ctx = (float*)d_out;          // [32*1024]
    float* out_w   = out_ctx + 32*1024;      // [32*2048]

    hipMemsetAsync(score, 0, 32*2048*sizeof(float), stream);
    hipMemsetAsync(out_ctx, 0, 32*1024*sizeof(float), stream);
    prep_k<<<dim3(768), 256, 0, stream>>>(query, Wa_w, Wa_b, Ua_b, Ua_w, qws, uat);
    score_gemm_fast<<<dim3(16, 4, 32), 256, 0, stream>>>(keys, uat, qws, Va_w, score);
    softmax_k<<<dim3(32),     256, 0, stream>>>(score, out_w);
    ctx_k    <<<dim3(32, 16), 256, 0, stream>>>(keys, out_w, out_ctx, 128);
}

// Round 6
// 619.588 us; speedup vs baseline: 1.0953x; 1.0953x over previous
//
#include <hip/hip_runtime.h>
#include <hip/hip_bf16.h>

// Bahdanau attention, MI355X. B=32, S=2048, H=1024, HL=2048.
// d_out: context[32,1,1024] ++ weights[32,1,2048]  (fp32)
//
// R11 = R9 (best, 622us) + fused pre-pass:
//   - pre_k: qproj (blocks 0..511) + uat^T (512..767) + kb16 cvt/permute
//     (768..8959) in ONE kernel -> the three independent input passes
//     overlap instead of serializing (~155us -> ~110us predicted).
//   - kb16 role widened: 32B read / 16B uint4 write per lane (was 16/8).
//   - R10's fp32-direct A staging REVERTED (8.4M bank conflicts: 128B rows
//     start every row at bank 0 -> slot-only banking -> 8-way pileup).
// score_gemm / softmax / ctx identical to R9 (proven: 178us, 0 conflicts).
//
// ws layout: qws 128K | uat 2M | score 256K(4M region) | 2M spare | kb16

typedef __attribute__((ext_vector_type(8))) short short8;
typedef __attribute__((ext_vector_type(4))) float floatx4;

typedef const __attribute__((address_space(1))) unsigned int gu32;
typedef __attribute__((address_space(3))) unsigned int lu32;

__device__ __forceinline__ unsigned short f2bf(float f) {
    union { float f; unsigned int u; } c; c.f = f;
    unsigned int u = c.u + 0x7fffu + ((c.u >> 16) & 1u);  // RNE
    return (unsigned short)(u >> 16);
}

// two fp32 -> packed bf16 pair (lo in bits 0..15), RNE either way
__device__ __forceinline__ unsigned int f2bf2(float lo, float hi) {
#if __has_builtin(__builtin_amdgcn_cvt_pk_bf16_f32)
    auto r = __builtin_amdgcn_cvt_pk_bf16_f32(lo, hi);
    unsigned int u; __builtin_memcpy(&u, &r, 4);
    return u;
#else
    return (unsigned int)f2bf(lo) | ((unsigned int)f2bf(hi) << 16);
#endif
}

// async global->LDS, 16B per lane; lane i's data lands at ldsbase + i*16.
__device__ __forceinline__ void gld16(const unsigned short* g, unsigned short* l) {
    __builtin_amdgcn_global_load_lds(
        (gu32*)(uintptr_t)g,
        (lu32*)(unsigned int)(uintptr_t)l,
        16, 0, 0);
}

// ---- kb16 chunk conversion: one thread = one 8-elem chunk (32B rd, 16B wr) --
// Layout (identical to R7/R8): row s, 32-elem group g, source chunk c lands
// at slot c^p, p = (s>>1)&3. Reads lane-contiguous (lane i: bytes 32i..32i+32).
__device__ __forceinline__ void kb16_chunk(const float* __restrict__ keys,
                                           unsigned short* __restrict__ kb,
                                           unsigned int t)
{
    unsigned int rg  = t >> 7;           // local row (b*2048 + s range)
    unsigned int rem = t & 127u;
    unsigned int g   = rem >> 2;         // 32-elem group
    unsigned int c   = rem & 3u;         // source chunk in group
    unsigned int p   = ((rg & 2047u) >> 1) & 3u;
    const float4* src = reinterpret_cast<const float4*>(keys + (size_t)rg*1024 + g*32 + c*8);
    float4 v0 = src[0], v1 = src[1];
    uint4 w;
    w.x = f2bf2(v0.x, v0.y); w.y = f2bf2(v0.z, v0.w);
    w.z = f2bf2(v1.x, v1.y); w.w = f2bf2(v1.z, v1.w);
    *reinterpret_cast<uint4*>(kb + (size_t)rg*1024 + g*32 + ((c ^ p) << 3)) = w;
}

// ---- K1: fused pre-pass ----
// blocks [0,512):   qproj: q[b,h] = sum_d query[b,d]*Wa[d,h] + Wa_b + Ua_b
// blocks [512,768): uat[h][d] = bf16(Ua[d][h])
// blocks [768,...): kb16 cvt+permute (kb_nch chunks, grid-stride x4)
__global__ __launch_bounds__(256) void pre_k(
    const float* __restrict__ query, const float* __restrict__ Wa,
    const float* __restrict__ Wab, const float* __restrict__ Uab,
    const float* __restrict__ Ua, const float* __restrict__ keys,
    float* __restrict__ qws, unsigned short* __restrict__ uat,
    unsigned short* __restrict__ kb, unsigned int kb_nch)
{
    __shared__ char smem[12288];
    const int tid = threadIdx.x;
    if (blockIdx.x < 512) {
        float* qs  = (float*)smem;          // 2048 f
        float* red = (float*)(smem + 8192); // 1024 f
        const int b = blockIdx.x >> 4, hc = blockIdx.x & 15;
        #pragma unroll
        for (int i = 0; i < 8; i++) qs[tid + 256*i] = query[b*2048 + tid + 256*i];
        __syncthreads();
        const int hq = tid & 15;      // h-quad within 64-h tile
        const int dg = tid >> 4;      // d-group (128 d each)
        const float4* wp = reinterpret_cast<const float4*>(Wa + (size_t)(dg*128)*1024 + hc*64 + hq*4);
        const float* qp = qs + dg*128;
        float4 a0; a0.x = a0.y = a0.z = a0.w = 0.f;
        float4 a1; a1.x = a1.y = a1.z = a1.w = 0.f;
        #pragma unroll 4
        for (int d = 0; d < 128; d += 2) {
            float q0 = qp[d], q1 = qp[d+1];
            float4 w0 = wp[(size_t)d*256];
            float4 w1 = wp[(size_t)(d+1)*256];
            a0.x += q0*w0.x; a0.y += q0*w0.y; a0.z += q0*w0.z; a0.w += q0*w0.w;
            a1.x += q1*w1.x; a1.y += q1*w1.y; a1.z += q1*w1.z; a1.w += q1*w1.w;
        }
        a0.x += a1.x; a0.y += a1.y; a0.z += a1.z; a0.w += a1.w;
        *reinterpret_cast<float4*>(red + dg*64 + hq*4) = a0;
        __syncthreads();
        if (tid < 64) {
            float v = 0.f;
            #pragma unroll
            for (int g = 0; g < 16; g++) v += red[g*64 + tid];
            int hh = hc*64 + tid;
            qws[b*1024 + hh] = v + Wab[hh] + Uab[hh];
        }
    } else if (blockIdx.x < 768) {
        typedef unsigned short row_t[65];
        row_t* t = (row_t*)smem;            // 64 x 65 ushort
        const int q = blockIdx.x - 512;
        const int x = tid & 63, yy = tid >> 6;
        const int d0 = (q >> 4)*64, h0 = (q & 15)*64;
        #pragma unroll
        for (int i = 0; i < 16; i++) {
            int y = yy*16 + i;
            t[y][x] = f2bf(Ua[(size_t)(d0+y)*1024 + h0 + x]);
        }
        __syncthreads();
        #pragma unroll
        for (int i = 0; i < 16; i++) {
            int y = yy*16 + i;
            uat[(size_t)(h0+y)*1024 + d0 + x] = t[x][y];
        }
    } else {
        const unsigned int stride = (gridDim.x - 768u) * 256u;
        unsigned int t = (blockIdx.x - 768u)*256u + tid;
        #pragma unroll 4
        for (int it = 0; it < 4; ++it, t += stride)
            if (t < kb_nch) kb16_chunk(keys, kb, t);
    }
}

// ---- standalone kb16 (fallback when workspace forces batch-chunking) ----
__global__ __launch_bounds__(256) void kb16_k(const float* __restrict__ keys,
                                              unsigned short* __restrict__ kb,
                                              unsigned int nch)
{
    const unsigned int stride = gridDim.x * 256u;
    unsigned int t = blockIdx.x * 256u + threadIdx.x;
    #pragma unroll 4
    for (int it = 0; it < 4; ++it, t += stride)
        if (t < nch) kb16_chunk(keys, kb, t);
}

// ---- K3: score GEMM 128(s) x 256(h) tile, both operands via global_load_lds ----
// (byte-identical to R9, proven 178us / 0 conflicts)
// LDS rows 64B (32 bf16), 16B chunks XOR-swizzled: slot = chunk ^ ((row>>1)&3).
// A: kb16 already stores the permutation -> linear gld16 (2 instrs/K-step).
// B: uat plain [h][d]; permutation applied via per-lane source offset.
// Frag reads (proven, 0 conflicts): base + row*32 + ((quad^((row>>1)&3))*8).
// Double-buffered, ONE barrier per K-step; per wave output 64(m) x 128(n),
// acc[4][8], 32 MFMA per thread-K-step.
// Epilogue: atomicAdd h-tile partial scores into score[32][2048].
__global__ __launch_bounds__(256) void score_gemm_fast(
    const unsigned short* __restrict__ kb16,  // [nb][2048][1024] bf16 permuted
    const unsigned short* __restrict__ uat,   // [1024][1024] bf16 [h][d]
    const float* __restrict__ qws,            // [32][1024]
    const float* __restrict__ Va,             // [1024]
    float* __restrict__ score,                // [32][2048] (pre-zeroed)
    int b0)                                   // batch offset of this chunk
{
    __shared__ unsigned short aS[2][128*32];  // 16KB
    __shared__ unsigned short bS[2][256*32];  // 32KB
    const int tid = threadIdx.x;
    const int bz = blockIdx.z;                 // local batch
    const int b = b0 + bz;                     // global batch
    const int s0 = blockIdx.x * 128;
    const int h0 = blockIdx.y * 256;
    const int lane = tid & 63, wave = tid >> 6;
    const int quad = lane >> 4, l15 = lane & 15;
    const int wm = (wave & 1) * 64, wn = (wave >> 1) * 128;

    // B-staging source (runtime-permuted, proven)
    const int srow = lane >> 2;
    const int schunk = (lane & 3) ^ ((srow >> 1) & 3);
    const unsigned short* ubase = uat + (size_t)h0*1024;
    size_t boff[4];
    #pragma unroll
    for (int u = 0; u < 4; u++) {
        int cg = wave*4 + u;                  // chunk-group 0..15 (16 rows each)
        boff[u] = (size_t)(cg*16 + srow)*1024 + schunk*8;
    }

    // A-staging source (baked-permuted, linear)
    const unsigned short* kA = kb16 + (size_t)(bz*2048 + s0)*1024;
    const size_t aoff0 = (size_t)(tid >> 2)*1024 + (size_t)(tid & 3)*8;
    const size_t aoff1 = (size_t)(64 + (tid >> 2))*1024 + (size_t)(tid & 3)*8;

    floatx4 acc[4][8];
    #pragma unroll
    for (int i = 0; i < 4; i++)
        #pragma unroll
        for (int j = 0; j < 8; j++) acc[i][j] = (floatx4)0.0f;

    // ---- prologue: stage tile 0 into buffer 0 ----
    gld16(kA + aoff0, aS[0] + wave*512);
    gld16(kA + aoff1, aS[0] + 2048 + wave*512);
    #pragma unroll
    for (int u = 0; u < 4; u++)
        gld16(ubase + boff[u], bS[0] + (wave*4 + u)*512);
    __syncthreads();

    int cur = 0;
    for (int kt = 0; kt < 31; ++kt) {
        const int nxt = cur ^ 1;
        const int k1 = (kt + 1) << 5;

        // prefetch tile kt+1 into idle buffer (6 async instrs, no VGPR traffic)
        gld16(kA + aoff0 + k1, aS[nxt] + wave*512);
        gld16(kA + aoff1 + k1, aS[nxt] + 2048 + wave*512);
        #pragma unroll
        for (int u = 0; u < 4; u++)
            gld16(ubase + boff[u] + k1, bS[nxt] + (wave*4 + u)*512);

        // compute tile kt from buf cur
        short8 af[4], bf8[8];
        #pragma unroll
        for (int i = 0; i < 4; i++) {
            int row = wm + 16*i + l15;
            af[i] = *reinterpret_cast<const short8*>(aS[cur] + row*32 + ((quad ^ ((row>>1)&3)) * 8));
        }
        #pragma unroll
        for (int j = 0; j < 8; j++) {
            int row = wn + 16*j + l15;
            bf8[j] = *reinterpret_cast<const short8*>(bS[cur] + row*32 + ((quad ^ ((row>>1)&3)) * 8));
        }
        #pragma unroll
        for (int i = 0; i < 4; i++)
            #pragma unroll
            for (int j = 0; j < 8; j++)
                acc[i][j] = __builtin_amdgcn_mfma_f32_16x16x32_bf16(af[i], bf8[j], acc[i][j], 0, 0, 0);

        __syncthreads();   // drains prefetch vmcnt + frag lgkm; one barrier/K-step
        cur = nxt;
    }

    // ---- last tile: compute only ----
    {
        short8 af[4], bf8[8];
        #pragma unroll
        for (int i = 0; i < 4; i++) {
            int row = wm + 16*i + l15;
            af[i] = *reinterpret_cast<const short8*>(aS[cur] + row*32 + ((quad ^ ((row>>1)&3)) * 8));
        }
        #pragma unroll
        for (int j = 0; j < 8; j++) {
            int row = wn + 16*j + l15;
            bf8[j] = *reinterpret_cast<const short8*>(bS[cur] + row*32 + ((quad ^ ((row>>1)&3)) * 8));
        }
        #pragma unroll
        for (int i = 0; i < 4; i++)
            #pragma unroll
            for (int j = 0; j < 8; j++)
                acc[i][j] = __builtin_amdgcn_mfma_f32_16x16x32_bf16(af[i], bf8[j], acc[i][j], 0, 0, 0);
    }

    // epilogue: p[s] = sum_n Va[n]*tanh(q[n]+k[s,n]); C-layout: n=lane&15, m=quad*4+reg
    float qv[8], vav[8];
    #pragma unroll
    for (int j = 0; j < 8; j++) {
        int n = h0 + wn + 16*j + l15;
        qv[j]  = qws[b*1024 + n];
        vav[j] = Va[n];
    }
    #pragma unroll
    for (int i = 0; i < 4; i++) {
        #pragma unroll
        for (int r = 0; r < 4; r++) {
            float p = 0.f;
            #pragma unroll
            for (int j = 0; j < 8; j++) {
                float x = qv[j] + acc[i][j][r];
                float e = __expf(2.f * x);                       // tanh = 1 - 2/(e^{2x}+1)
                float t = 1.f - 2.f * __builtin_amdgcn_rcpf(e + 1.f);
                p += vav[j] * t;
            }
            #pragma unroll
            for (int off = 1; off < 16; off <<= 1) p += __shfl_xor(p, off, 64);
            if (l15 == 0) {
                int m = wm + 16*i + quad*4 + r;
                atomicAdd(score + (size_t)b*2048 + s0 + m, p);
            }
        }
    }
}

// ---- K4: softmax over s per batch (single-pass; score pre-reduced) ----
__global__ __launch_bounds__(256) void softmax_k(const float* __restrict__ score,
                                                 float* __restrict__ out_w)
{
    const int tid = threadIdx.x;
    const int b = blockIdx.x;
    __shared__ float wred[4], wred2[4];
    float sc[8];
    float mx = -3.0e38f;
    #pragma unroll
    for (int i = 0; i < 8; i++) {
        sc[i] = score[(size_t)b*2048 + tid + 256*i];
        mx = fmaxf(mx, sc[i]);
    }
    #pragma unroll
    for (int off = 32; off >= 1; off >>= 1) mx = fmaxf(mx, __shfl_xor(mx, off, 64));
    if ((tid & 63) == 0) wred[tid >> 6] = mx;
    __syncthreads();
    mx = fmaxf(fmaxf(wred[0], wred[1]), fmaxf(wred[2], wred[3]));
    float e[8]; float lsum = 0.f;
    #pragma unroll
    for (int i = 0; i < 8; i++) { e[i] = __expf(sc[i] - mx); lsum += e[i]; }
    #pragma unroll
    for (int off = 32; off >= 1; off >>= 1) lsum += __shfl_xor(lsum, off, 64);
    if ((tid & 63) == 0) wred2[tid >> 6] = lsum;
    __syncthreads();
    float inv = 1.0f / (wred2[0] + wred2[1] + wred2[2] + wred2[3]);
    #pragma unroll
    for (int i = 0; i < 8; i++) out_w[b*2048 + tid + 256*i] = e[i] * inv;
}

// ---- K5: context accumulated directly into out_ctx via atomics ----
__global__ __launch_bounds__(256) void ctx_k(const float* __restrict__ keys,
                                             const float* __restrict__ w,
                                             float* __restrict__ out_ctx, int sper)
{
    const int tid = threadIdx.x;
    const int b = blockIdx.x, sc = blockIdx.y;
    const float4* k4 = reinterpret_cast<const float4*>(keys) + (size_t)(b*2048 + sc*sper)*256;
    const float* wp = w + b*2048 + sc*sper;
    float4 a; a.x = a.y = a.z = a.w = 0.f;
    #pragma unroll 4
    for (int s = 0; s < sper; s++) {
        float wv = wp[s];
        float4 kv = k4[(size_t)s*256 + tid];
        a.x += wv*kv.x; a.y += wv*kv.y; a.z += wv*kv.z; a.w += wv*kv.w;
    }
    float* o = out_ctx + (size_t)b*1024 + tid*4;
    atomicAdd(o + 0, a.x);
    atomicAdd(o + 1, a.y);
    atomicAdd(o + 2, a.z);
    atomicAdd(o + 3, a.w);
}

extern "C" void kernel_launch(void* const* d_in, const int* in_sizes, int n_in,
                              void* d_out, int out_size, void* d_ws, size_t ws_size,
                              hipStream_t stream)
{
    const float* query = (const float*)d_in[0];
    const float* keys  = (const float*)d_in[1];
    const float* Wa_w  = (const float*)d_in[2];
    const float* Wa_b  = (const float*)d_in[3];
    const float* Ua_w  = (const float*)d_in[4];
    const float* Ua_b  = (const float*)d_in[5];
    const float* Va_w  = (const float*)d_in[6];
    // d_in[7] (Va_b) is a uniform shift on scores -> softmax-invariant; unused.

    char* ws = (char*)d_ws;
    float*          qws   = (float*)(ws);                       // 128 KiB
    unsigned short* uat   = (unsigned short*)(ws + 131072);     // 2 MiB
    float*          score = (float*)(ws + 131072 + 2097152);    // 256 KiB (4M region)
    const size_t BASE = 131072 + 2097152 + 4194304 + 2097152;   // 8.52 MiB
    unsigned short* kb16 = (unsigned short*)(ws + BASE);

    // pick largest batch-chunk whose kb16 fits the remaining workspace
    size_t avail = (ws_size > BASE) ? (ws_size - BASE) : 0;
    int nb = 32;
    while (nb > 1 && (size_t)nb * 2048 * 1024 * 2 > avail) nb >>= 1;

    float* out_ctx = (float*)d_out;          // [32*1024]
    float* out_w   = out_ctx + 32*1024;      // [32*2048]

    hipMemsetAsync(score, 0, 32*2048*sizeof(float), stream);
    hipMemsetAsync(out_ctx, 0, 32*1024*sizeof(float), stream);

    if (nb == 32) {
        // fused pre-pass: qproj + uat + full kb16 in one launch
        const unsigned int nch = 32u * 2048u * 128u;            // 8.39M chunks
        pre_k<<<dim3(768 + 8192), 256, 0, stream>>>(
            query, Wa_w, Wa_b, Ua_b, Ua_w, keys, qws, uat, kb16, nch);
        score_gemm_fast<<<dim3(16, 4, 32), 256, 0, stream>>>(kb16, uat, qws, Va_w, score, 0);
    } else {
        pre_k<<<dim3(768), 256, 0, stream>>>(
            query, Wa_w, Wa_b, Ua_b, Ua_w, keys, qws, uat, kb16, 0u);
        for (int b0 = 0; b0 < 32; b0 += nb) {
            unsigned int nch = (unsigned int)nb * 2048u * 128u;
            unsigned int nblk = (nch/4u + 255u) / 256u;
            kb16_k<<<dim3(nblk), 256, 0, stream>>>(keys + (size_t)b0*2048*1024, kb16, nch);
            score_gemm_fast<<<dim3(16, 4, nb), 256, 0, stream>>>(kb16, uat, qws, Va_w, score, b0);
        }
    }
    softmax_k<<<dim3(32),     256, 0, stream>>>(score, out_w);
    ctx_k    <<<dim3(32, 16), 256, 0, stream>>>(keys, out_w, out_ctx, 128);
}